// Round 1
// baseline (8099.829 us; speedup 1.0000x reference)
//
#include <hip/hip_runtime.h>
#include <math.h>

#define NN 4096
#define BB 4
#define KK 20
#define OUTC 256
#define GN (BB*NN)

// ---------------- xx[b][n] = sum_c x[b][c][n]^2 ----------------
template<int C>
__global__ void __launch_bounds__(256) xx_kernel(const float* __restrict__ x, int bstride,
                                                 float* __restrict__ xxo) {
  int i = blockIdx.x*256 + threadIdx.x;
  int b = i >> 12, n = i & (NN-1);
  const float* xp = x + (size_t)b*bstride + n;
  float s = 0.f;
#pragma unroll
  for (int c = 0; c < C; ++c) { float v = xp[(size_t)c*NN]; s = fmaf(v, v, s); }
  xxo[i] = s;
}

// ---------------- KNN: top-20 by neg_dist = 2*x.q - xx[n] - xx[m] ----------------
// block = 256 threads = 4 waves; each wave owns one query point.
// Lane l scans columns m = 256*jp + 4*l + {0..3}; per-lane sorted top-20 kept in LDS
// (stride-256 columns -> 2-way bank aliasing only, free). Final in-wave merge via
// shfl butterfly argmax with (val desc, idx asc) comparator == jax.lax.top_k order.
template<int C>
__global__ void __launch_bounds__(256) knn_kernel(const float* __restrict__ x, int bstride,
                                                  const float* __restrict__ xxb,
                                                  int* __restrict__ idx_out) {
  __shared__ float qv[4][C];
  __shared__ float lval[KK*256];
  __shared__ int   lidx[KK*256];
  const int tid = threadIdx.x;
  const int w = tid >> 6, lane = tid & 63;
  const int g0 = blockIdx.x*4;
  const int b = g0 >> 12, n0 = g0 & (NN-1);
  for (int i = tid; i < 4*C; i += 256) {
    int ww = i / C, c = i - ww*C;
    qv[ww][c] = x[(size_t)b*bstride + (size_t)c*NN + (n0 + ww)];
  }
#pragma unroll
  for (int s = 0; s < KK; ++s) { lval[s*256+tid] = -INFINITY; lidx[s*256+tid] = 0x7fffffff; }
  __syncthreads();
  const int n = n0 + w;
  const float xxq = xxb[b*NN + n];
  float qreg[C];
#pragma unroll
  for (int c = 0; c < C; ++c) qreg[c] = qv[w][c];
  const float* xb  = x + (size_t)b*bstride;
  const float* xxr = xxb + b*NN;
  float minreg = -INFINITY;
#pragma unroll 1
  for (int jp = 0; jp < 16; ++jp) {
    const int m0 = jp*256 + lane*4;
    float a0=0.f, a1=0.f, a2=0.f, a3=0.f;
#pragma unroll
    for (int c = 0; c < C; ++c) {
      const float4 xv = *reinterpret_cast<const float4*>(xb + (size_t)c*NN + m0);
      const float q = qreg[c];
      a0 = fmaf(q, xv.x, a0); a1 = fmaf(q, xv.y, a1);
      a2 = fmaf(q, xv.z, a2); a3 = fmaf(q, xv.w, a3);
    }
    const float4 xm = *reinterpret_cast<const float4*>(xxr + m0);
    float dv[4];
    dv[0] = 2.f*a0 - xxq - xm.x; dv[1] = 2.f*a1 - xxq - xm.y;
    dv[2] = 2.f*a2 - xxq - xm.z; dv[3] = 2.f*a3 - xxq - xm.w;
#pragma unroll
    for (int ii = 0; ii < 4; ++ii) {
      const float d = dv[ii];
      if (d > minreg) {              // strict >: equal keeps earlier (smaller m) entry
        int p = KK-1;
        while (p > 0) {
          float vp = lval[(p-1)*256+tid];
          if (vp < d) {
            lval[p*256+tid] = vp;
            lidx[p*256+tid] = lidx[(p-1)*256+tid];
            --p;
          } else break;
        }
        lval[p*256+tid] = d;
        lidx[p*256+tid] = m0 + ii;
        minreg = lval[(KK-1)*256+tid];
      }
    }
  }
  // merge 64 per-lane sorted lists -> wave-global top-20
  int p = 0;
  int* outp = idx_out + (size_t)(b*NN + n)*KK;
#pragma unroll 1
  for (int r = 0; r < KK; ++r) {
    float h; int hi;
    if (p < KK) { h = lval[p*256+tid]; hi = lidx[p*256+tid]; }
    else        { h = -INFINITY;       hi = 0x7fffffff; }
    float v = h; int vi = hi;
#pragma unroll
    for (int s = 1; s < 64; s <<= 1) {
      float ov = __shfl_xor(v, s, 64);
      int   oi = __shfl_xor(vi, s, 64);
      if (ov > v || (ov == v && oi < vi)) { v = ov; vi = oi; }
    }
    if (h == v && hi == vi) ++p;     // unique winner advances (idx unique)
    if (lane == 0) outp[r] = vi;
  }
}

// ---------------- P = W1 . x,  Q = (W2-W1) . x   (both [b][n][o]) ----------------
template<int C, int O>
__global__ void __launch_bounds__(256) pq_kernel(const float* __restrict__ x, int bstride,
                                                 const float* __restrict__ W,
                                                 float* __restrict__ P, float* __restrict__ Q) {
  constexpr int CC = (C < 32) ? C : 32;
  constexpr int NPP = 256 / O;
  constexpr int NITER = 64 / NPP;
  __shared__ float xt[C*64];
  __shared__ float w1t[CC*O];
  __shared__ float wdt[CC*O];
  const int tid = threadIdx.x;
  const int g0 = blockIdx.x*64;
  const int b = g0 >> 12, n0 = g0 & (NN-1);
  for (int i = tid; i < C*64; i += 256) {
    int c = i >> 6, j = i & 63;
    xt[i] = x[(size_t)b*bstride + (size_t)c*NN + (n0 + j)];
  }
  const int o = tid % O;
  const int ns = tid / O;
  float ap[NITER], aq[NITER];
#pragma unroll
  for (int i = 0; i < NITER; ++i) { ap[i] = 0.f; aq[i] = 0.f; }
  for (int cc = 0; cc < C; cc += CC) {
    __syncthreads();
    for (int i = tid; i < CC*O; i += 256) {
      int oo = i % O, c = i / O;
      float w1 = W[oo*(2*C) + cc + c];
      float w2 = W[oo*(2*C) + C + cc + c];
      w1t[c*O + oo] = w1;
      wdt[c*O + oo] = w2 - w1;
    }
    __syncthreads();
#pragma unroll
    for (int np = 0; np < NITER; ++np) {
      const int nl = np*NPP + ns;
#pragma unroll
      for (int c = 0; c < CC; ++c) {
        float xv = xt[(cc + c)*64 + nl];
        ap[np] = fmaf(xv, w1t[c*O + o], ap[np]);
        aq[np] = fmaf(xv, wdt[c*O + o], aq[np]);
      }
    }
  }
#pragma unroll
  for (int np = 0; np < NITER; ++np) {
    const int nl = np*NPP + ns;
    size_t row = (size_t)(g0 + nl)*O + o;
    P[row] = ap[np];
    Q[row] = aq[np];
  }
}

// ---------------- y = P[m]+Q[n]: per-(b,n,o) max/min over k + per-channel partial sums ----
template<int O>
__global__ void __launch_bounds__(256) stats_kernel(const float* __restrict__ P,
                                                    const float* __restrict__ Q,
                                                    const int* __restrict__ idxb,
                                                    float* __restrict__ ymax,
                                                    float* __restrict__ ymin,
                                                    float* __restrict__ parts) {
  constexpr int NPB = 256 / O;
  __shared__ float ls[256], ls2[256];
  const int tid = threadIdx.x;
  const int o = tid % O, ns = tid / O;
  const int g = blockIdx.x*NPB + ns;
  const int b = g >> 12;
  const float qvv = Q[(size_t)g*O + o];
  const int* ip = idxb + (size_t)g*KK;
  const float* Pb = P + (size_t)b*NN*O;
  float s = 0.f, s2 = 0.f, mx = -INFINITY, mn = INFINITY;
#pragma unroll 4
  for (int k = 0; k < KK; ++k) {
    int m = ip[k];
    float yv = Pb[(size_t)m*O + o] + qvv;
    s += yv; s2 = fmaf(yv, yv, s2);
    mx = fmaxf(mx, yv); mn = fminf(mn, yv);
  }
  ymax[(size_t)g*O + o] = mx;
  ymin[(size_t)g*O + o] = mn;
  ls[tid] = s; ls2[tid] = s2;
  __syncthreads();
  if (ns == 0) {
#pragma unroll
    for (int j = 1; j < NPB; ++j) { s += ls[j*O + o]; s2 += ls2[j*O + o]; }
    parts[(size_t)blockIdx.x*2*O + o] = s;
    parts[(size_t)blockIdx.x*2*O + O + o] = s2;
  }
}

// ---------------- per-channel BN affine coefficients (deterministic f64 tree) ----------
template<int O>
__global__ void __launch_bounds__(256) reduce_kernel(const float* __restrict__ parts, int nblocks,
                                                     const float* __restrict__ gg,
                                                     const float* __restrict__ bbp,
                                                     float* __restrict__ chan) {
  __shared__ double sh[512];
  const int o = blockIdx.x, t = threadIdx.x;
  double S = 0.0, S2 = 0.0;
  for (int i = t; i < nblocks; i += 256) {
    S  += (double)parts[(size_t)i*2*O + o];
    S2 += (double)parts[(size_t)i*2*O + O + o];
  }
  sh[t] = S; sh[256+t] = S2;
  __syncthreads();
  for (int s = 128; s > 0; s >>= 1) {
    if (t < s) { sh[t] += sh[t+s]; sh[256+t] += sh[256+t+s]; }
    __syncthreads();
  }
  if (t == 0) {
    const double M = (double)BB*NN*KK;
    double mean = sh[0]/M;
    double var  = sh[256]/M - mean*mean;
    double inv  = 1.0/sqrt(var + 1e-5);
    double A  = (double)gg[o]*inv;
    double Bc = (double)bbp[o] - mean*A;
    chan[2*o]   = (float)A;
    chan[2*o+1] = (float)Bc;
  }
}

// ---------------- out[b][cbase+o][n] = leaky(A*(A>0?ymax:ymin)+Bc), LDS transpose ------
template<int O>
__global__ void __launch_bounds__(256) final_kernel(const float* __restrict__ ymax,
                                                    const float* __restrict__ ymin,
                                                    const float* __restrict__ chan,
                                                    float* __restrict__ out, int cbase) {
  __shared__ float buf[64*(O+1)];
  const int tid = threadIdx.x;
  const int g0 = blockIdx.x*64;
  const int b = g0 >> 12, n0 = g0 & (NN-1);
  for (int i = tid; i < 64*O; i += 256) {
    int o = i % O, nl = i / O;
    size_t r = (size_t)(g0 + nl)*O + o;
    float A = chan[2*o], Bc = chan[2*o+1];
    float v = (A > 0.f) ? ymax[r] : ymin[r];
    float y = fmaf(A, v, Bc);
    buf[nl*(O+1) + o] = (y > 0.f) ? y : 0.2f*y;
  }
  __syncthreads();
  for (int i = tid; i < 64*O; i += 256) {
    int nl = i & 63, o = i >> 6;
    out[(size_t)b*(OUTC*NN) + (size_t)(cbase + o)*NN + (n0 + nl)] = buf[nl*(O+1) + o];
  }
}

extern "C" void kernel_launch(void* const* d_in, const int* in_sizes, int n_in,
                              void* d_out, int out_size, void* d_ws, size_t ws_size,
                              hipStream_t stream) {
  (void)in_sizes; (void)n_in; (void)out_size; (void)ws_size;
  const float* x  = (const float*)d_in[0];
  const float* W0 = (const float*)d_in[1];
  const float* g0 = (const float*)d_in[2];
  const float* b0 = (const float*)d_in[3];
  const float* W1 = (const float*)d_in[4];
  const float* g1 = (const float*)d_in[5];
  const float* b1 = (const float*)d_in[6];
  const float* W2 = (const float*)d_in[7];
  const float* g2 = (const float*)d_in[8];
  const float* b2 = (const float*)d_in[9];
  float* out = (float*)d_out;
  char* ws = (char*)d_ws;

  float* xxb  = (float*)(ws);                       // 64 KB
  int*   idxb = (int*)  (ws + ((size_t)1<<20));     // 1.31 MB
  float* P    = (float*)(ws + ((size_t)4<<20));     // 8 MB
  float* Q    = (float*)(ws + ((size_t)12<<20));    // 8 MB
  float* ymax = (float*)(ws + ((size_t)20<<20));    // 8 MB
  float* ymin = (float*)(ws + ((size_t)28<<20));    // 8 MB
  float* prts = (float*)(ws + ((size_t)36<<20));    // 8 MB
  float* chan = (float*)(ws + ((size_t)44<<20));    // 1 KB

  // ---- layer 0: C=3 -> O=64, out channels [0,64) ----
  xx_kernel<3><<<GN/256, 256, 0, stream>>>(x, 3*NN, xxb);
  knn_kernel<3><<<GN/4, 256, 0, stream>>>(x, 3*NN, xxb, idxb);
  pq_kernel<3,64><<<GN/64, 256, 0, stream>>>(x, 3*NN, W0, P, Q);
  stats_kernel<64><<<GN/4, 256, 0, stream>>>(P, Q, idxb, ymax, ymin, prts);
  reduce_kernel<64><<<64, 256, 0, stream>>>(prts, GN/4, g0, b0, chan);
  final_kernel<64><<<GN/64, 256, 0, stream>>>(ymax, ymin, chan, out, 0);

  // ---- layer 1: C=64 -> O=64, input = out[:,0:64,:], out channels [64,128) ----
  const float* x1 = out;
  xx_kernel<64><<<GN/256, 256, 0, stream>>>(x1, OUTC*NN, xxb);
  knn_kernel<64><<<GN/4, 256, 0, stream>>>(x1, OUTC*NN, xxb, idxb);
  pq_kernel<64,64><<<GN/64, 256, 0, stream>>>(x1, OUTC*NN, W1, P, Q);
  stats_kernel<64><<<GN/4, 256, 0, stream>>>(P, Q, idxb, ymax, ymin, prts);
  reduce_kernel<64><<<64, 256, 0, stream>>>(prts, GN/4, g1, b1, chan);
  final_kernel<64><<<GN/64, 256, 0, stream>>>(ymax, ymin, chan, out, 64);

  // ---- layer 2: C=64 -> O=128, input = out[:,64:128,:], out channels [128,256) ----
  const float* x2 = out + (size_t)64*NN;
  xx_kernel<64><<<GN/256, 256, 0, stream>>>(x2, OUTC*NN, xxb);
  knn_kernel<64><<<GN/4, 256, 0, stream>>>(x2, OUTC*NN, xxb, idxb);
  pq_kernel<64,128><<<GN/64, 256, 0, stream>>>(x2, OUTC*NN, W2, P, Q);
  stats_kernel<128><<<GN/2, 256, 0, stream>>>(P, Q, idxb, ymax, ymin, prts);
  reduce_kernel<128><<<128, 256, 0, stream>>>(prts, GN/2, g2, b2, chan);
  final_kernel<128><<<GN/64, 256, 0, stream>>>(ymax, ymin, chan, out, 128);
}

// Round 2
// 4342.747 us; speedup vs baseline: 1.8651x; 1.8651x over previous
//
#include <hip/hip_runtime.h>
#include <math.h>

#define NN 4096
#define BB 4
#define KK 20
#define OUTC 256
#define GN (BB*NN)

// ---------------- xx[b][n] = sum_c x[b][c][n]^2 ----------------
template<int C>
__global__ void __launch_bounds__(256) xx_kernel(const float* __restrict__ x, int bstride,
                                                 float* __restrict__ xxo) {
  int i = blockIdx.x*256 + threadIdx.x;
  int b = i >> 12, n = i & (NN-1);
  const float* xp = x + (size_t)b*bstride + n;
  float s = 0.f;
#pragma unroll
  for (int c = 0; c < C; ++c) { float v = xp[(size_t)c*NN]; s = fmaf(v, v, s); }
  xxo[i] = s;
}

// ---------------- KNN pass 1: per (query-block, candidate-half) top-32 lists ----------
// Block = 256 threads = 16 query-groups(qg) x 16 cand-slices(mg).
// Thread owns an 8q x 8m accumulator tile; distances d = 2*acc - xxq - xxm (exact
// same fma order as the validated R1 kernel -> identical neighbor ranking).
// Each 16-lane group keeps an unsorted top-32 per query (2 slots/lane in VGPRs)
// with group-uniform threshold; inserts are rare ballot-driven replace-min butterflies.
template<int C>
__global__ void __launch_bounds__(256) knn_kernel(const float* __restrict__ x, int bstride,
                                                  const float* __restrict__ xxb,
                                                  float4* __restrict__ klist) {
  constexpr int MB = 128;
  constexpr int QB = 128;
  constexpr int CC = (C < 32) ? C : 32;
  __shared__ float q_lds[C][QB];
  __shared__ float xq_lds[QB];
  __shared__ float cand[CC][MB];
  __shared__ float xm_lds[MB];
  const int tid  = threadIdx.x;
  const int qb   = blockIdx.x >> 1;
  const int h    = blockIdx.x & 1;
  const int b    = qb >> 5;
  const int n0   = (qb & 31) << 7;
  const int qg   = tid >> 4;
  const int mg   = tid & 15;
  const int lane = tid & 63;
  const int L0   = lane & 48;
  const float* xb  = x + (size_t)b*bstride;
  const float* xxr = xxb + b*NN;

  for (int i = tid; i < C*QB; i += 256) {
    int c = i >> 7, jj = i & (QB-1);
    q_lds[c][jj] = xb[(size_t)c*NN + n0 + jj];
  }
  if (tid < QB) xq_lds[tid] = xxr[n0 + tid];
  __syncthreads();
  float xq[8];
#pragma unroll
  for (int i = 0; i < 8; ++i) xq[i] = xq_lds[qg*8 + i];

  float tv[8][2]; int ti[8][2]; float thr[8];
#pragma unroll
  for (int i = 0; i < 8; ++i) {
    tv[i][0] = tv[i][1] = -INFINITY;
    ti[i][0] = ti[i][1] = 0x7fffffff;
    thr[i] = -INFINITY;
  }

  const int m_base = h*(NN/2);
  for (int mt = 0; mt < (NN/2)/MB; ++mt) {
    const int mt0 = m_base + mt*MB;

    float acc[8][8];
#pragma unroll
    for (int i = 0; i < 8; ++i)
#pragma unroll
      for (int j = 0; j < 8; ++j) acc[i][j] = 0.f;

    for (int cc0 = 0; cc0 < C; cc0 += CC) {
      __syncthreads();
      for (int i = tid; i < CC*MB; i += 256) {
        int c = i >> 7, m = i & (MB-1);
        cand[c][m] = xb[(size_t)(cc0 + c)*NN + mt0 + m];
      }
      if (cc0 == 0 && tid < MB) xm_lds[tid] = xxr[mt0 + tid];
      __syncthreads();
#pragma unroll 8
      for (int c = 0; c < CC; ++c) {
        float4 qa  = *reinterpret_cast<const float4*>(&q_lds[cc0 + c][qg*8]);
        float4 qc  = *reinterpret_cast<const float4*>(&q_lds[cc0 + c][qg*8 + 4]);
        float4 ma  = *reinterpret_cast<const float4*>(&cand[c][mg*8]);
        float4 mb2 = *reinterpret_cast<const float4*>(&cand[c][mg*8 + 4]);
        float qq[8] = {qa.x,qa.y,qa.z,qa.w,qc.x,qc.y,qc.z,qc.w};
        float mm[8] = {ma.x,ma.y,ma.z,ma.w,mb2.x,mb2.y,mb2.z,mb2.w};
#pragma unroll
        for (int i = 0; i < 8; ++i)
#pragma unroll
          for (int j = 0; j < 8; ++j) acc[i][j] = fmaf(qq[i], mm[j], acc[i][j]);
      }
    }

    float4 xma = *reinterpret_cast<const float4*>(&xm_lds[mg*8]);
    float4 xmb = *reinterpret_cast<const float4*>(&xm_lds[mg*8 + 4]);
    float xm[8] = {xma.x,xma.y,xma.z,xma.w,xmb.x,xmb.y,xmb.z,xmb.w};

    const bool first = (mt == 0);
#pragma unroll
    for (int i = 0; i < 8; ++i) {
      float dv[8];
#pragma unroll
      for (int j = 0; j < 8; ++j) dv[j] = 2.f*acc[i][j] - xq[i] - xm[j];
      bool ins = false;
      if (first) {
        // bootstrap: first 32 candidates of the half fill the 32 slots directly
        tv[i][0] = dv[0]; ti[i][0] = mt0 + mg*8 + 0;
        tv[i][1] = dv[1]; ti[i][1] = mt0 + mg*8 + 1;
        float mv = fminf(tv[i][0], tv[i][1]);
#pragma unroll
        for (int t = 1; t < 16; t <<= 1) mv = fminf(mv, __shfl_xor(mv, t, 64));
        thr[i] = mv;
      }
      bool anyp = false;
#pragma unroll
      for (int j = 0; j < 8; ++j) if (!(first && j < 2)) anyp |= (dv[j] > thr[i]);
      unsigned long long balany = __ballot(anyp);
      if ((balany >> L0) & 0xffffull) {
#pragma unroll
        for (int j = 0; j < 8; ++j) {
          if (first && j < 2) continue;
          unsigned long long bal = __ballot(dv[j] > thr[i]);
          unsigned msk = (unsigned)((bal >> L0) & 0xffffull);
          while (msk) {
            int s = __ffs(msk) - 1;
            msk &= msk - 1;
            float cv = __shfl(dv[j], L0 + s, 64);
            int ci = mt0 + s*8 + j;
            // group-wide min over the 32 slots (val asc, loc asc tie)
            bool sel1 = tv[i][1] < tv[i][0];
            float mval = sel1 ? tv[i][1] : tv[i][0];
            int mloc = (mg << 1) | (sel1 ? 1 : 0);
#pragma unroll
            for (int t = 1; t < 16; t <<= 1) {
              float ov = __shfl_xor(mval, t, 64);
              int   ol = __shfl_xor(mloc, t, 64);
              if (ov < mval || (ov == mval && ol < mloc)) { mval = ov; mloc = ol; }
            }
            if (cv > mval) {
              bool w0 = (mloc == (mg << 1));
              bool w1 = (mloc == ((mg << 1) | 1));
              tv[i][0] = w0 ? cv : tv[i][0]; ti[i][0] = w0 ? ci : ti[i][0];
              tv[i][1] = w1 ? cv : tv[i][1]; ti[i][1] = w1 ? ci : ti[i][1];
              ins = true;
            }
          }
        }
      }
      if (ins) {
        float mv = fminf(tv[i][0], tv[i][1]);
#pragma unroll
        for (int t = 1; t < 16; t <<= 1) mv = fminf(mv, __shfl_xor(mv, t, 64));
        thr[i] = mv;
      }
    }
  }

#pragma unroll
  for (int i = 0; i < 8; ++i) {
    int q = n0 + qg*8 + i;
    klist[((size_t)(b*NN + q)*2 + h)*16 + mg] =
      make_float4(tv[i][0], __int_as_float(ti[i][0]), tv[i][1], __int_as_float(ti[i][1]));
  }
}

// ---------------- KNN pass 2: merge two top-32 lists -> jax-ordered top-20 ----------
__global__ void __launch_bounds__(256) knn_merge_kernel(const float4* __restrict__ klist,
                                                        int* __restrict__ idx_out) {
  const int tid = threadIdx.x;
  const int hw = tid >> 5, l = tid & 31;
  const int q = blockIdx.x*8 + hw;
  float4 e = klist[(size_t)q*32 + l];
  float v0 = e.x, v1 = e.z;
  int i0 = __float_as_int(e.y), i1 = __float_as_int(e.w);
  int* outp = idx_out + (size_t)q*KK;
  for (int r = 0; r < KK; ++r) {
    bool s1 = (v1 > v0) || (v1 == v0 && i1 < i0);
    float bv = s1 ? v1 : v0; int bi = s1 ? i1 : i0;
#pragma unroll
    for (int t = 1; t < 32; t <<= 1) {
      float ov = __shfl_xor(bv, t, 64);
      int   oi = __shfl_xor(bi, t, 64);
      if (ov > bv || (ov == bv && oi < bi)) { bv = ov; bi = oi; }
    }
    if (v0 == bv && i0 == bi)      { v0 = -INFINITY; i0 = 0x7fffffff; }
    else if (v1 == bv && i1 == bi) { v1 = -INFINITY; i1 = 0x7fffffff; }
    if (l == 0) outp[r] = bi;
  }
}

// ---------------- P = W1 . x,  Q = (W2-W1) . x   (both [b][n][o]) ----------------
template<int C, int O>
__global__ void __launch_bounds__(256) pq_kernel(const float* __restrict__ x, int bstride,
                                                 const float* __restrict__ W,
                                                 float* __restrict__ P, float* __restrict__ Q) {
  constexpr int CC = (C < 32) ? C : 32;
  constexpr int NPP = 256 / O;
  constexpr int NITER = 64 / NPP;
  __shared__ float xt[C*64];
  __shared__ float w1t[CC*O];
  __shared__ float wdt[CC*O];
  const int tid = threadIdx.x;
  const int g0 = blockIdx.x*64;
  const int b = g0 >> 12, n0 = g0 & (NN-1);
  for (int i = tid; i < C*64; i += 256) {
    int c = i >> 6, j = i & 63;
    xt[i] = x[(size_t)b*bstride + (size_t)c*NN + (n0 + j)];
  }
  const int o = tid % O;
  const int ns = tid / O;
  float ap[NITER], aq[NITER];
#pragma unroll
  for (int i = 0; i < NITER; ++i) { ap[i] = 0.f; aq[i] = 0.f; }
  for (int cc = 0; cc < C; cc += CC) {
    __syncthreads();
    for (int i = tid; i < CC*O; i += 256) {
      int oo = i % O, c = i / O;
      float w1 = W[oo*(2*C) + cc + c];
      float w2 = W[oo*(2*C) + C + cc + c];
      w1t[c*O + oo] = w1;
      wdt[c*O + oo] = w2 - w1;
    }
    __syncthreads();
#pragma unroll
    for (int np = 0; np < NITER; ++np) {
      const int nl = np*NPP + ns;
#pragma unroll
      for (int c = 0; c < CC; ++c) {
        float xv = xt[(cc + c)*64 + nl];
        ap[np] = fmaf(xv, w1t[c*O + o], ap[np]);
        aq[np] = fmaf(xv, wdt[c*O + o], aq[np]);
      }
    }
  }
#pragma unroll
  for (int np = 0; np < NITER; ++np) {
    const int nl = np*NPP + ns;
    size_t row = (size_t)(g0 + nl)*O + o;
    P[row] = ap[np];
    Q[row] = aq[np];
  }
}

// ---------------- y = P[m]+Q[n]: per-(b,n,o) max/min over k + per-channel partial sums ----
template<int O>
__global__ void __launch_bounds__(256) stats_kernel(const float* __restrict__ P,
                                                    const float* __restrict__ Q,
                                                    const int* __restrict__ idxb,
                                                    float* __restrict__ ymax,
                                                    float* __restrict__ ymin,
                                                    float* __restrict__ parts) {
  constexpr int NPB = 256 / O;
  __shared__ float ls[256], ls2[256];
  const int tid = threadIdx.x;
  const int o = tid % O, ns = tid / O;
  const int g = blockIdx.x*NPB + ns;
  const int b = g >> 12;
  const float qvv = Q[(size_t)g*O + o];
  const int* ip = idxb + (size_t)g*KK;
  const float* Pb = P + (size_t)b*NN*O;
  float s = 0.f, s2 = 0.f, mx = -INFINITY, mn = INFINITY;
#pragma unroll 4
  for (int k = 0; k < KK; ++k) {
    int m = ip[k];
    float yv = Pb[(size_t)m*O + o] + qvv;
    s += yv; s2 = fmaf(yv, yv, s2);
    mx = fmaxf(mx, yv); mn = fminf(mn, yv);
  }
  ymax[(size_t)g*O + o] = mx;
  ymin[(size_t)g*O + o] = mn;
  ls[tid] = s; ls2[tid] = s2;
  __syncthreads();
  if (ns == 0) {
#pragma unroll
    for (int j = 1; j < NPB; ++j) { s += ls[j*O + o]; s2 += ls2[j*O + o]; }
    parts[(size_t)blockIdx.x*2*O + o] = s;
    parts[(size_t)blockIdx.x*2*O + O + o] = s2;
  }
}

// ---------------- per-channel BN affine coefficients (deterministic f64 tree) ----------
template<int O>
__global__ void __launch_bounds__(256) reduce_kernel(const float* __restrict__ parts, int nblocks,
                                                     const float* __restrict__ gg,
                                                     const float* __restrict__ bbp,
                                                     float* __restrict__ chan) {
  __shared__ double sh[512];
  const int o = blockIdx.x, t = threadIdx.x;
  double S = 0.0, S2 = 0.0;
  for (int i = t; i < nblocks; i += 256) {
    S  += (double)parts[(size_t)i*2*O + o];
    S2 += (double)parts[(size_t)i*2*O + O + o];
  }
  sh[t] = S; sh[256+t] = S2;
  __syncthreads();
  for (int s = 128; s > 0; s >>= 1) {
    if (t < s) { sh[t] += sh[t+s]; sh[256+t] += sh[256+t+s]; }
    __syncthreads();
  }
  if (t == 0) {
    const double M = (double)BB*NN*KK;
    double mean = sh[0]/M;
    double var  = sh[256]/M - mean*mean;
    double inv  = 1.0/sqrt(var + 1e-5);
    double A  = (double)gg[o]*inv;
    double Bc = (double)bbp[o] - mean*A;
    chan[2*o]   = (float)A;
    chan[2*o+1] = (float)Bc;
  }
}

// ---------------- out[b][cbase+o][n] = leaky(A*(A>0?ymax:ymin)+Bc), LDS transpose ------
template<int O>
__global__ void __launch_bounds__(256) final_kernel(const float* __restrict__ ymax,
                                                    const float* __restrict__ ymin,
                                                    const float* __restrict__ chan,
                                                    float* __restrict__ out, int cbase) {
  __shared__ float buf[64*(O+1)];
  const int tid = threadIdx.x;
  const int g0 = blockIdx.x*64;
  const int b = g0 >> 12, n0 = g0 & (NN-1);
  for (int i = tid; i < 64*O; i += 256) {
    int o = i % O, nl = i / O;
    size_t r = (size_t)(g0 + nl)*O + o;
    float A = chan[2*o], Bc = chan[2*o+1];
    float v = (A > 0.f) ? ymax[r] : ymin[r];
    float y = fmaf(A, v, Bc);
    buf[nl*(O+1) + o] = (y > 0.f) ? y : 0.2f*y;
  }
  __syncthreads();
  for (int i = tid; i < 64*O; i += 256) {
    int nl = i & 63, o = i >> 6;
    out[(size_t)b*(OUTC*NN) + (size_t)(cbase + o)*NN + (n0 + nl)] = buf[nl*(O+1) + o];
  }
}

extern "C" void kernel_launch(void* const* d_in, const int* in_sizes, int n_in,
                              void* d_out, int out_size, void* d_ws, size_t ws_size,
                              hipStream_t stream) {
  (void)in_sizes; (void)n_in; (void)out_size; (void)ws_size;
  const float* x  = (const float*)d_in[0];
  const float* W0 = (const float*)d_in[1];
  const float* g0 = (const float*)d_in[2];
  const float* b0 = (const float*)d_in[3];
  const float* W1 = (const float*)d_in[4];
  const float* g1 = (const float*)d_in[5];
  const float* b1 = (const float*)d_in[6];
  const float* W2 = (const float*)d_in[7];
  const float* g2 = (const float*)d_in[8];
  const float* b2 = (const float*)d_in[9];
  float* out = (float*)d_out;
  char* ws = (char*)d_ws;

  float*  xxb  = (float*) (ws);                       // 64 KB
  int*    idxb = (int*)   (ws + ((size_t)1<<20));     // 1.31 MB
  float*  P    = (float*) (ws + ((size_t)4<<20));     // 8 MB
  float*  Q    = (float*) (ws + ((size_t)12<<20));    // 8 MB
  float*  ymax = (float*) (ws + ((size_t)20<<20));    // 8 MB
  float*  ymin = (float*) (ws + ((size_t)28<<20));    // 8 MB
  float*  prts = (float*) (ws + ((size_t)36<<20));    // 8 MB (also knn klist)
  float4* klst = (float4*)(ws + ((size_t)36<<20));
  float*  chan = (float*) (ws + ((size_t)44<<20));    // 1 KB

  // ---- layer 0: C=3 -> O=64, out channels [0,64) ----
  xx_kernel<3><<<GN/256, 256, 0, stream>>>(x, 3*NN, xxb);
  knn_kernel<3><<<2*(GN/128), 256, 0, stream>>>(x, 3*NN, xxb, klst);
  knn_merge_kernel<<<GN/8, 256, 0, stream>>>(klst, idxb);
  pq_kernel<3,64><<<GN/64, 256, 0, stream>>>(x, 3*NN, W0, P, Q);
  stats_kernel<64><<<GN/4, 256, 0, stream>>>(P, Q, idxb, ymax, ymin, prts);
  reduce_kernel<64><<<64, 256, 0, stream>>>(prts, GN/4, g0, b0, chan);
  final_kernel<64><<<GN/64, 256, 0, stream>>>(ymax, ymin, chan, out, 0);

  // ---- layer 1: C=64 -> O=64, input = out[:,0:64,:], out channels [64,128) ----
  const float* x1 = out;
  xx_kernel<64><<<GN/256, 256, 0, stream>>>(x1, OUTC*NN, xxb);
  knn_kernel<64><<<2*(GN/128), 256, 0, stream>>>(x1, OUTC*NN, xxb, klst);
  knn_merge_kernel<<<GN/8, 256, 0, stream>>>(klst, idxb);
  pq_kernel<64,64><<<GN/64, 256, 0, stream>>>(x1, OUTC*NN, W1, P, Q);
  stats_kernel<64><<<GN/4, 256, 0, stream>>>(P, Q, idxb, ymax, ymin, prts);
  reduce_kernel<64><<<64, 256, 0, stream>>>(prts, GN/4, g1, b1, chan);
  final_kernel<64><<<GN/64, 256, 0, stream>>>(ymax, ymin, chan, out, 64);

  // ---- layer 2: C=64 -> O=128, input = out[:,64:128,:], out channels [128,256) ----
  const float* x2 = out + (size_t)64*NN;
  xx_kernel<64><<<GN/256, 256, 0, stream>>>(x2, OUTC*NN, xxb);
  knn_kernel<64><<<2*(GN/128), 256, 0, stream>>>(x2, OUTC*NN, xxb, klst);
  knn_merge_kernel<<<GN/8, 256, 0, stream>>>(klst, idxb);
  pq_kernel<64,128><<<GN/64, 256, 0, stream>>>(x2, OUTC*NN, W2, P, Q);
  stats_kernel<128><<<GN/2, 256, 0, stream>>>(P, Q, idxb, ymax, ymin, prts);
  reduce_kernel<128><<<128, 256, 0, stream>>>(prts, GN/2, g2, b2, chan);
  final_kernel<128><<<GN/64, 256, 0, stream>>>(ymax, ymin, chan, out, 128);
}

// Round 3
// 1121.193 us; speedup vs baseline: 7.2243x; 3.8733x over previous
//
#include <hip/hip_runtime.h>
#include <math.h>

#define NN 4096
#define BB 4
#define KK 20
#define OUTC 256
#define GN (BB*NN)

// ---------------- xx[b][n] = sum_c x[b][c][n]^2 ----------------
template<int C>
__global__ void __launch_bounds__(256) xx_kernel(const float* __restrict__ x, int bstride,
                                                 float* __restrict__ xxo) {
  int i = blockIdx.x*256 + threadIdx.x;
  int b = i >> 12, n = i & (NN-1);
  const float* xp = x + (size_t)b*bstride + n;
  float s = 0.f;
#pragma unroll
  for (int c = 0; c < C; ++c) { float v = xp[(size_t)c*NN]; s = fmaf(v, v, s); }
  xxo[i] = s;
}

// ---------------- KNN: per-lane sorted top-6 + 20-round wave argmax merge ----------
// Block = 256 thr = 4 waves; each wave owns 4 queries; QB=16 queries/block.
// Tiles of MB=512 candidates; lane's 8 m per tile: lane*4+{0..3} and 256+lane*4+{0..3}
// (lane-contiguous 16B LDS reads -> minimal bank conflicts). Stream per (lane,query)
// is m-ascending, so strict-> sorted insert gives jax tie order (val desc, idx asc).
// Exactness: if a lane contributes all 6 slots to the top-20, flag query for cleanup.
template<int C>
__global__ void __launch_bounds__(256) knn2_kernel(const float* __restrict__ x, int bstride,
                                                   const float* __restrict__ xxb,
                                                   int* __restrict__ idx_out,
                                                   int* __restrict__ flag_cnt,
                                                   int* __restrict__ flag_list) {
  constexpr int CC = (C < 16) ? C : 16;
  constexpr int S = 6;
  __shared__ float cand[CC][512];
  __shared__ float q_lds[CC][16];
  __shared__ float xm_lds[512];
  __shared__ float xq_lds[16];
  const int tid = threadIdx.x;
  const int wq = tid >> 6, lane = tid & 63;
  const int qb = blockIdx.x;
  const int b = qb >> 8, n0 = (qb & 255) << 4;
  const float* xb  = x + (size_t)b*bstride;
  const float* xxr = xxb + b*NN;

  if (tid < 16) xq_lds[tid] = xxr[n0 + tid];
  __syncthreads();
  float xq[4];
#pragma unroll
  for (int i = 0; i < 4; ++i) xq[i] = xq_lds[wq*4 + i];

  float sv[4][S]; int si[4][S];
#pragma unroll
  for (int i = 0; i < 4; ++i)
#pragma unroll
    for (int k = 0; k < S; ++k) { sv[i][k] = -INFINITY; si[i][k] = 0x7fffffff; }

  for (int t = 0; t < NN/512; ++t) {
    const int mt0 = t*512;
    float acc[4][8];
#pragma unroll
    for (int i = 0; i < 4; ++i)
#pragma unroll
      for (int j = 0; j < 8; ++j) acc[i][j] = 0.f;

    for (int cc0 = 0; cc0 < C; cc0 += CC) {
      __syncthreads();
      for (int v = tid; v < CC*128; v += 256) {
        int c = v >> 7, mc = (v & 127) * 4;
        *reinterpret_cast<float4*>(&cand[c][mc]) =
          *reinterpret_cast<const float4*>(&xb[(size_t)(cc0 + c)*NN + mt0 + mc]);
      }
      if (tid < CC*16) { int c = tid >> 4, i = tid & 15; q_lds[c][i] = xb[(size_t)(cc0 + c)*NN + n0 + i]; }
      if (cc0 == 0 && tid < 128)
        *reinterpret_cast<float4*>(&xm_lds[tid*4]) =
          *reinterpret_cast<const float4*>(&xxr[mt0 + tid*4]);
      __syncthreads();
#pragma unroll 4
      for (int c = 0; c < CC; ++c) {
        float4 qa = *reinterpret_cast<const float4*>(&q_lds[c][wq*4]);   // uniform -> broadcast
        float4 ca = *reinterpret_cast<const float4*>(&cand[c][lane*4]);
        float4 cb = *reinterpret_cast<const float4*>(&cand[c][256 + lane*4]);
        float qq[4] = {qa.x, qa.y, qa.z, qa.w};
        float mm[8] = {ca.x, ca.y, ca.z, ca.w, cb.x, cb.y, cb.z, cb.w};
#pragma unroll
        for (int i = 0; i < 4; ++i)
#pragma unroll
          for (int j = 0; j < 8; ++j) acc[i][j] = fmaf(qq[i], mm[j], acc[i][j]);
      }
    }

    float4 xma = *reinterpret_cast<const float4*>(&xm_lds[lane*4]);
    float4 xmb = *reinterpret_cast<const float4*>(&xm_lds[256 + lane*4]);
    float xmv[8] = {xma.x, xma.y, xma.z, xma.w, xmb.x, xmb.y, xmb.z, xmb.w};

#pragma unroll
    for (int i = 0; i < 4; ++i) {
#pragma unroll
      for (int j = 0; j < 8; ++j) {
        const float d = 2.f*acc[i][j] - xq[i] - xmv[j];
        const int mi = mt0 + ((j < 4) ? (lane*4 + j) : (256 + lane*4 + (j - 4)));
        // branchless sorted insert (desc; strict > keeps earlier=smaller idx first on ties)
        bool c0 = d > sv[i][0], c1 = d > sv[i][1], c2 = d > sv[i][2];
        bool c3 = d > sv[i][3], c4 = d > sv[i][4], c5 = d > sv[i][5];
        sv[i][5] = c4 ? sv[i][4] : (c5 ? d : sv[i][5]);  si[i][5] = c4 ? si[i][4] : (c5 ? mi : si[i][5]);
        sv[i][4] = c3 ? sv[i][3] : (c4 ? d : sv[i][4]);  si[i][4] = c3 ? si[i][3] : (c4 ? mi : si[i][4]);
        sv[i][3] = c2 ? sv[i][2] : (c3 ? d : sv[i][3]);  si[i][3] = c2 ? si[i][2] : (c3 ? mi : si[i][3]);
        sv[i][2] = c1 ? sv[i][1] : (c2 ? d : sv[i][2]);  si[i][2] = c1 ? si[i][1] : (c2 ? mi : si[i][2]);
        sv[i][1] = c0 ? sv[i][0] : (c1 ? d : sv[i][1]);  si[i][1] = c0 ? si[i][0] : (c1 ? mi : si[i][1]);
        sv[i][0] = c0 ? d : sv[i][0];                    si[i][0] = c0 ? mi : si[i][0];
      }
    }
  }

  // merge: 20 rounds of wave argmax over lane heads (val desc, idx asc == jax order)
#pragma unroll 1
  for (int i = 0; i < 4; ++i) {
    const int q = n0 + wq*4 + i;
    int* outp = idx_out + (size_t)(b*NN + q)*KK;
    int consumed = 0;
#pragma unroll 1
    for (int r = 0; r < KK; ++r) {
      float bv = sv[i][0]; int bi = si[i][0];
#pragma unroll
      for (int s = 1; s < 64; s <<= 1) {
        float ov = __shfl_xor(bv, s, 64);
        int   oi = __shfl_xor(bi, s, 64);
        if (ov > bv || (ov == bv && oi < bi)) { bv = ov; bi = oi; }
      }
      if (lane == 0) outp[r] = bi;
      if (si[i][0] == bi && sv[i][0] == bv) {
        sv[i][0] = sv[i][1]; si[i][0] = si[i][1];
        sv[i][1] = sv[i][2]; si[i][1] = si[i][2];
        sv[i][2] = sv[i][3]; si[i][2] = si[i][3];
        sv[i][3] = sv[i][4]; si[i][3] = si[i][4];
        sv[i][4] = sv[i][5]; si[i][4] = si[i][5];
        sv[i][5] = -INFINITY; si[i][5] = 0x7fffffff;
        ++consumed;
      }
    }
    if (__ballot(consumed >= S)) {
      if (lane == 0) { int p = atomicAdd(flag_cnt, 1); flag_list[p & 4095] = b*NN + q; }
    }
  }
}

// ---------------- exact cleanup for flagged queries (rare; ~1 block per query) ------
template<int C>
__global__ void __launch_bounds__(256) knn_fix_kernel(const float* __restrict__ x, int bstride,
                                                      const float* __restrict__ xxb,
                                                      const int* __restrict__ flag_cnt,
                                                      const int* __restrict__ flag_list,
                                                      int* __restrict__ idx_out) {
  __shared__ float redv[4]; __shared__ int redi[4];
  const int tid = threadIdx.x;
  const int wid = tid >> 6, lane = tid & 63;
  const int cnt = flag_cnt[0] < 4096 ? flag_cnt[0] : 4096;
  for (int f = blockIdx.x; f < cnt; f += gridDim.x) {
    const int qn = flag_list[f];
    const int b = qn >> 12, n = qn & (NN-1);
    const float* xb  = x + (size_t)b*bstride;
    const float* xxr = xxb + b*NN;
    float acc[16];
#pragma unroll
    for (int jj = 0; jj < 16; ++jj) acc[jj] = 0.f;
    for (int c = 0; c < C; ++c) {
      const float qc = xb[(size_t)c*NN + n];
      const float* row = xb + (size_t)c*NN + tid;
#pragma unroll
      for (int jj = 0; jj < 16; ++jj) acc[jj] = fmaf(qc, row[256*jj], acc[jj]);
    }
    const float xq = xxr[n];
    float dv[16]; int di[16]; unsigned used = 0;
#pragma unroll
    for (int jj = 0; jj < 16; ++jj) {
      dv[jj] = 2.f*acc[jj] - xq - xxr[tid + 256*jj];
      di[jj] = tid + 256*jj;
    }
    for (int r = 0; r < KK; ++r) {
      float bv = -INFINITY; int bi = 0x7fffffff;
#pragma unroll
      for (int jj = 0; jj < 16; ++jj) {
        bool ok = !((used >> jj) & 1);
        bool bet = ok && (dv[jj] > bv || (dv[jj] == bv && di[jj] < bi));
        bv = bet ? dv[jj] : bv; bi = bet ? di[jj] : bi;
      }
#pragma unroll
      for (int s = 1; s < 64; s <<= 1) {
        float ov = __shfl_xor(bv, s, 64);
        int   oi = __shfl_xor(bi, s, 64);
        if (ov > bv || (ov == bv && oi < bi)) { bv = ov; bi = oi; }
      }
      if (lane == 0) { redv[wid] = bv; redi[wid] = bi; }
      __syncthreads();
#pragma unroll
      for (int w = 0; w < 4; ++w) {
        float ov = redv[w]; int oi = redi[w];
        if (ov > bv || (ov == bv && oi < bi)) { bv = ov; bi = oi; }
      }
      __syncthreads();
      // owner marks used; one thread owns bi
      if ((bi & 255) == tid) used |= 1u << (bi >> 8);
      if (tid == 0) idx_out[(size_t)qn*KK + r] = bi;
    }
  }
}

// ---------------- P = W1 . x,  Q = (W2-W1) . x   (both [b][n][o]) ----------------
template<int C, int O>
__global__ void __launch_bounds__(256) pq_kernel(const float* __restrict__ x, int bstride,
                                                 const float* __restrict__ W,
                                                 float* __restrict__ P, float* __restrict__ Q) {
  constexpr int CC = (C < 32) ? C : 32;
  constexpr int NPP = 256 / O;
  constexpr int NITER = 64 / NPP;
  __shared__ float xt[C*64];
  __shared__ float w1t[CC*O];
  __shared__ float wdt[CC*O];
  const int tid = threadIdx.x;
  const int g0 = blockIdx.x*64;
  const int b = g0 >> 12, n0 = g0 & (NN-1);
  for (int i = tid; i < C*64; i += 256) {
    int c = i >> 6, j = i & 63;
    xt[i] = x[(size_t)b*bstride + (size_t)c*NN + (n0 + j)];
  }
  const int o = tid % O;
  const int ns = tid / O;
  float ap[NITER], aq[NITER];
#pragma unroll
  for (int i = 0; i < NITER; ++i) { ap[i] = 0.f; aq[i] = 0.f; }
  for (int cc = 0; cc < C; cc += CC) {
    __syncthreads();
    for (int i = tid; i < CC*O; i += 256) {
      int oo = i % O, c = i / O;
      float w1 = W[oo*(2*C) + cc + c];
      float w2 = W[oo*(2*C) + C + cc + c];
      w1t[c*O + oo] = w1;
      wdt[c*O + oo] = w2 - w1;
    }
    __syncthreads();
#pragma unroll
    for (int np = 0; np < NITER; ++np) {
      const int nl = np*NPP + ns;
#pragma unroll
      for (int c = 0; c < CC; ++c) {
        float xv = xt[(cc + c)*64 + nl];
        ap[np] = fmaf(xv, w1t[c*O + o], ap[np]);
        aq[np] = fmaf(xv, wdt[c*O + o], aq[np]);
      }
    }
  }
#pragma unroll
  for (int np = 0; np < NITER; ++np) {
    const int nl = np*NPP + ns;
    size_t row = (size_t)(g0 + nl)*O + o;
    P[row] = ap[np];
    Q[row] = aq[np];
  }
}

// ---------------- y = P[m]+Q[n]: per-(b,n,o) max/min over k + per-channel partial sums ----
template<int O>
__global__ void __launch_bounds__(256) stats_kernel(const float* __restrict__ P,
                                                    const float* __restrict__ Q,
                                                    const int* __restrict__ idxb,
                                                    float* __restrict__ ymax,
                                                    float* __restrict__ ymin,
                                                    float* __restrict__ parts) {
  constexpr int NPB = 256 / O;
  __shared__ float ls[256], ls2[256];
  const int tid = threadIdx.x;
  const int o = tid % O, ns = tid / O;
  const int g = blockIdx.x*NPB + ns;
  const int b = g >> 12;
  const float qvv = Q[(size_t)g*O + o];
  const int* ip = idxb + (size_t)g*KK;
  const float* Pb = P + (size_t)b*NN*O;
  float s = 0.f, s2 = 0.f, mx = -INFINITY, mn = INFINITY;
#pragma unroll 4
  for (int k = 0; k < KK; ++k) {
    int m = ip[k];
    float yv = Pb[(size_t)m*O + o] + qvv;
    s += yv; s2 = fmaf(yv, yv, s2);
    mx = fmaxf(mx, yv); mn = fminf(mn, yv);
  }
  ymax[(size_t)g*O + o] = mx;
  ymin[(size_t)g*O + o] = mn;
  ls[tid] = s; ls2[tid] = s2;
  __syncthreads();
  if (ns == 0) {
#pragma unroll
    for (int j = 1; j < NPB; ++j) { s += ls[j*O + o]; s2 += ls2[j*O + o]; }
    parts[(size_t)blockIdx.x*2*O + o] = s;
    parts[(size_t)blockIdx.x*2*O + O + o] = s2;
  }
}

// ---------------- per-channel BN affine coefficients (deterministic f64 tree) ----------
template<int O>
__global__ void __launch_bounds__(256) reduce_kernel(const float* __restrict__ parts, int nblocks,
                                                     const float* __restrict__ gg,
                                                     const float* __restrict__ bbp,
                                                     float* __restrict__ chan) {
  __shared__ double sh[512];
  const int o = blockIdx.x, t = threadIdx.x;
  double S = 0.0, S2 = 0.0;
  for (int i = t; i < nblocks; i += 256) {
    S  += (double)parts[(size_t)i*2*O + o];
    S2 += (double)parts[(size_t)i*2*O + O + o];
  }
  sh[t] = S; sh[256+t] = S2;
  __syncthreads();
  for (int s = 128; s > 0; s >>= 1) {
    if (t < s) { sh[t] += sh[t+s]; sh[256+t] += sh[256+t+s]; }
    __syncthreads();
  }
  if (t == 0) {
    const double M = (double)BB*NN*KK;
    double mean = sh[0]/M;
    double var  = sh[256]/M - mean*mean;
    double inv  = 1.0/sqrt(var + 1e-5);
    double A  = (double)gg[o]*inv;
    double Bc = (double)bbp[o] - mean*A;
    chan[2*o]   = (float)A;
    chan[2*o+1] = (float)Bc;
  }
}

// ---------------- out[b][cbase+o][n] = leaky(A*(A>0?ymax:ymin)+Bc), LDS transpose ------
template<int O>
__global__ void __launch_bounds__(256) final_kernel(const float* __restrict__ ymax,
                                                    const float* __restrict__ ymin,
                                                    const float* __restrict__ chan,
                                                    float* __restrict__ out, int cbase) {
  __shared__ float buf[64*(O+1)];
  const int tid = threadIdx.x;
  const int g0 = blockIdx.x*64;
  const int b = g0 >> 12, n0 = g0 & (NN-1);
  for (int i = tid; i < 64*O; i += 256) {
    int o = i % O, nl = i / O;
    size_t r = (size_t)(g0 + nl)*O + o;
    float A = chan[2*o], Bc = chan[2*o+1];
    float v = (A > 0.f) ? ymax[r] : ymin[r];
    float y = fmaf(A, v, Bc);
    buf[nl*(O+1) + o] = (y > 0.f) ? y : 0.2f*y;
  }
  __syncthreads();
  for (int i = tid; i < 64*O; i += 256) {
    int nl = i & 63, o = i >> 6;
    out[(size_t)b*(OUTC*NN) + (size_t)(cbase + o)*NN + (n0 + nl)] = buf[nl*(O+1) + o];
  }
}

extern "C" void kernel_launch(void* const* d_in, const int* in_sizes, int n_in,
                              void* d_out, int out_size, void* d_ws, size_t ws_size,
                              hipStream_t stream) {
  (void)in_sizes; (void)n_in; (void)out_size; (void)ws_size;
  const float* x  = (const float*)d_in[0];
  const float* W0 = (const float*)d_in[1];
  const float* g0 = (const float*)d_in[2];
  const float* b0 = (const float*)d_in[3];
  const float* W1 = (const float*)d_in[4];
  const float* g1 = (const float*)d_in[5];
  const float* b1 = (const float*)d_in[6];
  const float* W2 = (const float*)d_in[7];
  const float* g2 = (const float*)d_in[8];
  const float* b2 = (const float*)d_in[9];
  float* out = (float*)d_out;
  char* ws = (char*)d_ws;

  float* xxb  = (float*)(ws);                       // 64 KB
  int*   idxb = (int*)  (ws + ((size_t)1<<20));     // 1.31 MB
  float* P    = (float*)(ws + ((size_t)4<<20));     // 8 MB
  float* Q    = (float*)(ws + ((size_t)12<<20));    // 8 MB
  float* ymax = (float*)(ws + ((size_t)20<<20));    // 8 MB
  float* ymin = (float*)(ws + ((size_t)28<<20));    // 8 MB
  float* prts = (float*)(ws + ((size_t)36<<20));    // 8 MB
  float* chan = (float*)(ws + ((size_t)44<<20));    // 1 KB
  int*   fcnt = (int*)  (ws + ((size_t)45<<20));    // 3 ints
  int*   flst = (int*)  (ws + ((size_t)45<<20) + 64); // 3*4096 ints

  hipMemsetAsync(fcnt, 0, 3*sizeof(int), stream);

  // ---- layer 0: C=3 -> O=64, out channels [0,64) ----
  xx_kernel<3><<<GN/256, 256, 0, stream>>>(x, 3*NN, xxb);
  knn2_kernel<3><<<GN/16, 256, 0, stream>>>(x, 3*NN, xxb, idxb, fcnt+0, flst+0*4096);
  knn_fix_kernel<3><<<16, 256, 0, stream>>>(x, 3*NN, xxb, fcnt+0, flst+0*4096, idxb);
  pq_kernel<3,64><<<GN/64, 256, 0, stream>>>(x, 3*NN, W0, P, Q);
  stats_kernel<64><<<GN/4, 256, 0, stream>>>(P, Q, idxb, ymax, ymin, prts);
  reduce_kernel<64><<<64, 256, 0, stream>>>(prts, GN/4, g0, b0, chan);
  final_kernel<64><<<GN/64, 256, 0, stream>>>(ymax, ymin, chan, out, 0);

  // ---- layer 1: C=64 -> O=64, input = out[:,0:64,:], out channels [64,128) ----
  const float* x1 = out;
  xx_kernel<64><<<GN/256, 256, 0, stream>>>(x1, OUTC*NN, xxb);
  knn2_kernel<64><<<GN/16, 256, 0, stream>>>(x1, OUTC*NN, xxb, idxb, fcnt+1, flst+1*4096);
  knn_fix_kernel<64><<<16, 256, 0, stream>>>(x1, OUTC*NN, xxb, fcnt+1, flst+1*4096, idxb);
  pq_kernel<64,64><<<GN/64, 256, 0, stream>>>(x1, OUTC*NN, W1, P, Q);
  stats_kernel<64><<<GN/4, 256, 0, stream>>>(P, Q, idxb, ymax, ymin, prts);
  reduce_kernel<64><<<64, 256, 0, stream>>>(prts, GN/4, g1, b1, chan);
  final_kernel<64><<<GN/64, 256, 0, stream>>>(ymax, ymin, chan, out, 64);

  // ---- layer 2: C=64 -> O=128, input = out[:,64:128,:], out channels [128,256) ----
  const float* x2 = out + (size_t)64*NN;
  xx_kernel<64><<<GN/256, 256, 0, stream>>>(x2, OUTC*NN, xxb);
  knn2_kernel<64><<<GN/16, 256, 0, stream>>>(x2, OUTC*NN, xxb, idxb, fcnt+2, flst+2*4096);
  knn_fix_kernel<64><<<16, 256, 0, stream>>>(x2, OUTC*NN, xxb, fcnt+2, flst+2*4096, idxb);
  pq_kernel<64,128><<<GN/64, 256, 0, stream>>>(x2, OUTC*NN, W2, P, Q);
  stats_kernel<128><<<GN/2, 256, 0, stream>>>(P, Q, idxb, ymax, ymin, prts);
  reduce_kernel<128><<<128, 256, 0, stream>>>(prts, GN/2, g2, b2, chan);
  final_kernel<128><<<GN/64, 256, 0, stream>>>(ymax, ymin, chan, out, 128);
}

// Round 4
// 786.436 us; speedup vs baseline: 10.2994x; 1.4257x over previous
//
#include <hip/hip_runtime.h>
#include <math.h>

#define NN 4096
#define BB 4
#define KK 20
#define OUTC 256
#define GN (BB*NN)

// ---------------- xx[b][n] = sum_c x[b][c][n]^2 ----------------
template<int C>
__global__ void __launch_bounds__(256) xx_kernel(const float* __restrict__ x, int bstride,
                                                 float* __restrict__ xxo) {
  int i = blockIdx.x*256 + threadIdx.x;
  int b = i >> 12, n = i & (NN-1);
  const float* xp = x + (size_t)b*bstride + n;
  float s = 0.f;
#pragma unroll
  for (int c = 0; c < C; ++c) { float v = xp[(size_t)c*NN]; s = fmaf(v, v, s); }
  xxo[i] = s;
}

__device__ __forceinline__ unsigned ord_u32(float v) {
  unsigned b = __float_as_uint(v);
  return (b & 0x80000000u) ? ~b : (b | 0x80000000u);
}

// Exact top-KK extraction from 64 lanes x S register slots via ballot bit-bisect.
// Order semantics: (value desc, idx asc) == jax.lax.top_k. Emits the index SET
// (downstream sum/max over k is order-invariant). Returns per-lane count kept.
template<int S>
__device__ __forceinline__ int extract_top20(const float (&sv)[S], const int (&si)[S],
                                             int* __restrict__ outp,
                                             unsigned long long lmask) {
  unsigned u[S];
#pragma unroll
  for (int k = 0; k < S; ++k) u[k] = ord_u32(sv[k]);
  // value bisect: largest T with count(u >= T) >= KK  -> T = 20th-largest value
  unsigned T = 0u;
#pragma unroll 1
  for (int bit = 31; bit >= 0; --bit) {
    unsigned Tp = T | (1u << bit);
    int c = 0;
#pragma unroll
    for (int k = 0; k < S; ++k) c += __popcll(__ballot(u[k] >= Tp));
    if (c >= KK) T = Tp;
  }
  int cgt = 0;
#pragma unroll
  for (int k = 0; k < S; ++k) cgt += __popcll(__ballot(u[k] > T));
  const int r = KK - cgt;  // how many value-ties to keep (smallest idx first)
  // idx bisect among equals: largest A with count(eq && idx < A) < r -> A = r-th smallest idx
  int A = 0;
#pragma unroll 1
  for (int bit = 11; bit >= 0; --bit) {
    int Ap = A | (1 << bit);
    int c = 0;
#pragma unroll
    for (int k = 0; k < S; ++k) c += __popcll(__ballot(u[k] == T && si[k] < Ap));
    if (c < r) A = Ap;
  }
  // emit: val > T, or val == T && idx <= A   (exactly KK entries)
  int base = 0, nk = 0;
#pragma unroll
  for (int k = 0; k < S; ++k) {
    bool kp = (u[k] > T) || (u[k] == T && si[k] <= A);
    unsigned long long mk = __ballot(kp);
    int pos = base + __popcll(mk & lmask);
    if (kp) outp[pos] = si[k];
    base += __popcll(mk);
    nk += kp ? 1 : 0;
  }
  return nk;
}

// ---------------- KNN: per-lane sorted top-6 + ballot-bisect extraction ----------
// Block = 256 thr = 4 waves; each wave owns 4 queries; 16 queries/block.
// Tiles of 512 candidates; lane's 8 m per tile: lane*4+{0..3} and 256+lane*4+{0..3}.
// Distance fma chain order identical to the R1/R3-validated kernels.
// Exactness: if a lane contributes all 6 slots to the top-20, flag query for cleanup.
template<int C>
__global__ void __launch_bounds__(256, 4) knn2_kernel(const float* __restrict__ x, int bstride,
                                                      const float* __restrict__ xxb,
                                                      int* __restrict__ idx_out,
                                                      int* __restrict__ flag_cnt,
                                                      int* __restrict__ flag_list) {
  constexpr int CC = (C < 16) ? C : 16;
  constexpr int S = 6;
  __shared__ float cand[CC][512];
  __shared__ float q_lds[CC][16];
  __shared__ float xm_lds[512];
  __shared__ float xq_lds[16];
  const int tid = threadIdx.x;
  const int wq = tid >> 6, lane = tid & 63;
  const unsigned long long lmask = (1ull << lane) - 1ull;
  const int qb = blockIdx.x;
  const int b = qb >> 8, n0 = (qb & 255) << 4;
  const float* xb  = x + (size_t)b*bstride;
  const float* xxr = xxb + b*NN;

  if (tid < 16) xq_lds[tid] = xxr[n0 + tid];
  __syncthreads();
  float xq[4];
#pragma unroll
  for (int i = 0; i < 4; ++i) xq[i] = xq_lds[wq*4 + i];

  float sv[4][S]; int si[4][S];
#pragma unroll
  for (int i = 0; i < 4; ++i)
#pragma unroll
    for (int k = 0; k < S; ++k) { sv[i][k] = -INFINITY; si[i][k] = 0x7fffffff; }

  for (int t = 0; t < NN/512; ++t) {
    const int mt0 = t*512;
    float acc[4][8];
#pragma unroll
    for (int i = 0; i < 4; ++i)
#pragma unroll
      for (int j = 0; j < 8; ++j) acc[i][j] = 0.f;

    for (int cc0 = 0; cc0 < C; cc0 += CC) {
      __syncthreads();
      for (int v = tid; v < CC*128; v += 256) {
        int c = v >> 7, mc = (v & 127) * 4;
        *reinterpret_cast<float4*>(&cand[c][mc]) =
          *reinterpret_cast<const float4*>(&xb[(size_t)(cc0 + c)*NN + mt0 + mc]);
      }
      if (tid < CC*16) { int c = tid >> 4, i = tid & 15; q_lds[c][i] = xb[(size_t)(cc0 + c)*NN + n0 + i]; }
      if (cc0 == 0 && tid < 128)
        *reinterpret_cast<float4*>(&xm_lds[tid*4]) =
          *reinterpret_cast<const float4*>(&xxr[mt0 + tid*4]);
      __syncthreads();
#pragma unroll 4
      for (int c = 0; c < CC; ++c) {
        float4 qa = *reinterpret_cast<const float4*>(&q_lds[c][wq*4]);   // uniform -> broadcast
        float4 ca = *reinterpret_cast<const float4*>(&cand[c][lane*4]);
        float4 cb = *reinterpret_cast<const float4*>(&cand[c][256 + lane*4]);
        float qq[4] = {qa.x, qa.y, qa.z, qa.w};
        float mm[8] = {ca.x, ca.y, ca.z, ca.w, cb.x, cb.y, cb.z, cb.w};
#pragma unroll
        for (int i = 0; i < 4; ++i)
#pragma unroll
          for (int j = 0; j < 8; ++j) acc[i][j] = fmaf(qq[i], mm[j], acc[i][j]);
      }
    }

    float4 xma = *reinterpret_cast<const float4*>(&xm_lds[lane*4]);
    float4 xmb = *reinterpret_cast<const float4*>(&xm_lds[256 + lane*4]);
    float xmv[8] = {xma.x, xma.y, xma.z, xma.w, xmb.x, xmb.y, xmb.z, xmb.w};

#pragma unroll
    for (int i = 0; i < 4; ++i) {
#pragma unroll
      for (int j = 0; j < 8; ++j) {
        const float d = 2.f*acc[i][j] - xq[i] - xmv[j];
        const int mi = mt0 + ((j < 4) ? (lane*4 + j) : (256 + lane*4 + (j - 4)));
        // branchless sorted insert (desc; strict > keeps earlier=smaller idx first on ties)
        bool c0 = d > sv[i][0], c1 = d > sv[i][1], c2 = d > sv[i][2];
        bool c3 = d > sv[i][3], c4 = d > sv[i][4], c5 = d > sv[i][5];
        sv[i][5] = c4 ? sv[i][4] : (c5 ? d : sv[i][5]);  si[i][5] = c4 ? si[i][4] : (c5 ? mi : si[i][5]);
        sv[i][4] = c3 ? sv[i][3] : (c4 ? d : sv[i][4]);  si[i][4] = c3 ? si[i][3] : (c4 ? mi : si[i][4]);
        sv[i][3] = c2 ? sv[i][2] : (c3 ? d : sv[i][3]);  si[i][3] = c2 ? si[i][2] : (c3 ? mi : si[i][3]);
        sv[i][2] = c1 ? sv[i][1] : (c2 ? d : sv[i][2]);  si[i][2] = c1 ? si[i][1] : (c2 ? mi : si[i][2]);
        sv[i][1] = c0 ? sv[i][0] : (c1 ? d : sv[i][1]);  si[i][1] = c0 ? si[i][0] : (c1 ? mi : si[i][1]);
        sv[i][0] = c0 ? d : sv[i][0];                    si[i][0] = c0 ? mi : si[i][0];
      }
    }
  }

  // extraction: fully unrolled over the 4 queries (static register indexing)
#pragma unroll
  for (int i = 0; i < 4; ++i) {
    const int q = n0 + wq*4 + i;
    int* outp = idx_out + (size_t)(b*NN + q)*KK;
    int nk = extract_top20<S>(sv[i], si[i], outp, lmask);
    if (__ballot(nk >= S)) {
      if (lane == 0) { int p = atomicAdd(flag_cnt, 1); flag_list[p & 4095] = b*NN + q; }
    }
  }
}

// ---------------- exact cleanup for flagged queries (rare; ~1 block per query) ------
template<int C>
__global__ void __launch_bounds__(256) knn_fix_kernel(const float* __restrict__ x, int bstride,
                                                      const float* __restrict__ xxb,
                                                      const int* __restrict__ flag_cnt,
                                                      const int* __restrict__ flag_list,
                                                      int* __restrict__ idx_out) {
  __shared__ float redv[4]; __shared__ int redi[4];
  const int tid = threadIdx.x;
  const int wid = tid >> 6, lane = tid & 63;
  const int cnt = flag_cnt[0] < 4096 ? flag_cnt[0] : 4096;
  for (int f = blockIdx.x; f < cnt; f += gridDim.x) {
    const int qn = flag_list[f];
    const int b = qn >> 12, n = qn & (NN-1);
    const float* xb  = x + (size_t)b*bstride;
    const float* xxr = xxb + b*NN;
    float acc[16];
#pragma unroll
    for (int jj = 0; jj < 16; ++jj) acc[jj] = 0.f;
    for (int c = 0; c < C; ++c) {
      const float qc = xb[(size_t)c*NN + n];
      const float* row = xb + (size_t)c*NN + tid;
#pragma unroll
      for (int jj = 0; jj < 16; ++jj) acc[jj] = fmaf(qc, row[256*jj], acc[jj]);
    }
    const float xq = xxr[n];
    float dv[16]; int di[16]; unsigned used = 0;
#pragma unroll
    for (int jj = 0; jj < 16; ++jj) {
      dv[jj] = 2.f*acc[jj] - xq - xxr[tid + 256*jj];
      di[jj] = tid + 256*jj;
    }
    for (int r = 0; r < KK; ++r) {
      float bv = -INFINITY; int bi = 0x7fffffff;
#pragma unroll
      for (int jj = 0; jj < 16; ++jj) {
        bool ok = !((used >> jj) & 1);
        bool bet = ok && (dv[jj] > bv || (dv[jj] == bv && di[jj] < bi));
        bv = bet ? dv[jj] : bv; bi = bet ? di[jj] : bi;
      }
#pragma unroll
      for (int s = 1; s < 64; s <<= 1) {
        float ov = __shfl_xor(bv, s, 64);
        int   oi = __shfl_xor(bi, s, 64);
        if (ov > bv || (ov == bv && oi < bi)) { bv = ov; bi = oi; }
      }
      if (lane == 0) { redv[wid] = bv; redi[wid] = bi; }
      __syncthreads();
#pragma unroll
      for (int w = 0; w < 4; ++w) {
        float ov = redv[w]; int oi = redi[w];
        if (ov > bv || (ov == bv && oi < bi)) { bv = ov; bi = oi; }
      }
      __syncthreads();
      if ((bi & 255) == tid) used |= 1u << (bi >> 8);
      if (tid == 0) idx_out[(size_t)qn*KK + r] = bi;
    }
  }
}

// ---------------- P = W1 . x,  Q = (W2-W1) . x   (both [b][n][o]) ----------------
template<int C, int O>
__global__ void __launch_bounds__(256) pq_kernel(const float* __restrict__ x, int bstride,
                                                 const float* __restrict__ W,
                                                 float* __restrict__ P, float* __restrict__ Q) {
  constexpr int CC = (C < 32) ? C : 32;
  constexpr int NPP = 256 / O;
  constexpr int NITER = 64 / NPP;
  __shared__ float xt[C*64];
  __shared__ float w1t[CC*O];
  __shared__ float wdt[CC*O];
  const int tid = threadIdx.x;
  const int g0 = blockIdx.x*64;
  const int b = g0 >> 12, n0 = g0 & (NN-1);
  for (int i = tid; i < C*64; i += 256) {
    int c = i >> 6, j = i & 63;
    xt[i] = x[(size_t)b*bstride + (size_t)c*NN + (n0 + j)];
  }
  const int o = tid % O;
  const int ns = tid / O;
  float ap[NITER], aq[NITER];
#pragma unroll
  for (int i = 0; i < NITER; ++i) { ap[i] = 0.f; aq[i] = 0.f; }
  for (int cc = 0; cc < C; cc += CC) {
    __syncthreads();
    for (int i = tid; i < CC*O; i += 256) {
      int oo = i % O, c = i / O;
      float w1 = W[oo*(2*C) + cc + c];
      float w2 = W[oo*(2*C) + C + cc + c];
      w1t[c*O + oo] = w1;
      wdt[c*O + oo] = w2 - w1;
    }
    __syncthreads();
#pragma unroll
    for (int np = 0; np < NITER; ++np) {
      const int nl = np*NPP + ns;
#pragma unroll
      for (int c = 0; c < CC; ++c) {
        float xv = xt[(cc + c)*64 + nl];
        ap[np] = fmaf(xv, w1t[c*O + o], ap[np]);
        aq[np] = fmaf(xv, wdt[c*O + o], aq[np]);
      }
    }
  }
#pragma unroll
  for (int np = 0; np < NITER; ++np) {
    const int nl = np*NPP + ns;
    size_t row = (size_t)(g0 + nl)*O + o;
    P[row] = ap[np];
    Q[row] = aq[np];
  }
}

// ---------------- y = P[m]+Q[n]: per-(b,n,o) max/min over k + per-channel partial sums ----
template<int O>
__global__ void __launch_bounds__(256) stats_kernel(const float* __restrict__ P,
                                                    const float* __restrict__ Q,
                                                    const int* __restrict__ idxb,
                                                    float* __restrict__ ymax,
                                                    float* __restrict__ ymin,
                                                    float* __restrict__ parts) {
  constexpr int NPB = 256 / O;
  __shared__ float ls[256], ls2[256];
  const int tid = threadIdx.x;
  const int o = tid % O, ns = tid / O;
  const int g = blockIdx.x*NPB + ns;
  const int b = g >> 12;
  const float qvv = Q[(size_t)g*O + o];
  const int* ip = idxb + (size_t)g*KK;
  const float* Pb = P + (size_t)b*NN*O;
  float s = 0.f, s2 = 0.f, mx = -INFINITY, mn = INFINITY;
#pragma unroll 4
  for (int k = 0; k < KK; ++k) {
    int m = ip[k];
    float yv = Pb[(size_t)m*O + o] + qvv;
    s += yv; s2 = fmaf(yv, yv, s2);
    mx = fmaxf(mx, yv); mn = fminf(mn, yv);
  }
  ymax[(size_t)g*O + o] = mx;
  ymin[(size_t)g*O + o] = mn;
  ls[tid] = s; ls2[tid] = s2;
  __syncthreads();
  if (ns == 0) {
#pragma unroll
    for (int j = 1; j < NPB; ++j) { s += ls[j*O + o]; s2 += ls2[j*O + o]; }
    parts[(size_t)blockIdx.x*2*O + o] = s;
    parts[(size_t)blockIdx.x*2*O + O + o] = s2;
  }
}

// ---------------- per-channel BN affine coefficients (deterministic f64 tree) ----------
template<int O>
__global__ void __launch_bounds__(256) reduce_kernel(const float* __restrict__ parts, int nblocks,
                                                     const float* __restrict__ gg,
                                                     const float* __restrict__ bbp,
                                                     float* __restrict__ chan) {
  __shared__ double sh[512];
  const int o = blockIdx.x, t = threadIdx.x;
  double S = 0.0, S2 = 0.0;
  for (int i = t; i < nblocks; i += 256) {
    S  += (double)parts[(size_t)i*2*O + o];
    S2 += (double)parts[(size_t)i*2*O + O + o];
  }
  sh[t] = S; sh[256+t] = S2;
  __syncthreads();
  for (int s = 128; s > 0; s >>= 1) {
    if (t < s) { sh[t] += sh[t+s]; sh[256+t] += sh[256+t+s]; }
    __syncthreads();
  }
  if (t == 0) {
    const double M = (double)BB*NN*KK;
    double mean = sh[0]/M;
    double var  = sh[256]/M - mean*mean;
    double inv  = 1.0/sqrt(var + 1e-5);
    double A  = (double)gg[o]*inv;
    double Bc = (double)bbp[o] - mean*A;
    chan[2*o]   = (float)A;
    chan[2*o+1] = (float)Bc;
  }
}

// ---------------- out[b][cbase+o][n] = leaky(A*(A>0?ymax:ymin)+Bc), LDS transpose ------
template<int O>
__global__ void __launch_bounds__(256) final_kernel(const float* __restrict__ ymax,
                                                    const float* __restrict__ ymin,
                                                    const float* __restrict__ chan,
                                                    float* __restrict__ out, int cbase) {
  __shared__ float buf[64*(O+1)];
  const int tid = threadIdx.x;
  const int g0 = blockIdx.x*64;
  const int b = g0 >> 12, n0 = g0 & (NN-1);
  for (int i = tid; i < 64*O; i += 256) {
    int o = i % O, nl = i / O;
    size_t r = (size_t)(g0 + nl)*O + o;
    float A = chan[2*o], Bc = chan[2*o+1];
    float v = (A > 0.f) ? ymax[r] : ymin[r];
    float y = fmaf(A, v, Bc);
    buf[nl*(O+1) + o] = (y > 0.f) ? y : 0.2f*y;
  }
  __syncthreads();
  for (int i = tid; i < 64*O; i += 256) {
    int nl = i & 63, o = i >> 6;
    out[(size_t)b*(OUTC*NN) + (size_t)(cbase + o)*NN + (n0 + nl)] = buf[nl*(O+1) + o];
  }
}

extern "C" void kernel_launch(void* const* d_in, const int* in_sizes, int n_in,
                              void* d_out, int out_size, void* d_ws, size_t ws_size,
                              hipStream_t stream) {
  (void)in_sizes; (void)n_in; (void)out_size; (void)ws_size;
  const float* x  = (const float*)d_in[0];
  const float* W0 = (const float*)d_in[1];
  const float* g0 = (const float*)d_in[2];
  const float* b0 = (const float*)d_in[3];
  const float* W1 = (const float*)d_in[4];
  const float* g1 = (const float*)d_in[5];
  const float* b1 = (const float*)d_in[6];
  const float* W2 = (const float*)d_in[7];
  const float* g2 = (const float*)d_in[8];
  const float* b2 = (const float*)d_in[9];
  float* out = (float*)d_out;
  char* ws = (char*)d_ws;

  float* xxb  = (float*)(ws);                       // 64 KB
  int*   idxb = (int*)  (ws + ((size_t)1<<20));     // 1.31 MB
  float* P    = (float*)(ws + ((size_t)4<<20));     // 8 MB
  float* Q    = (float*)(ws + ((size_t)12<<20));    // 8 MB
  float* ymax = (float*)(ws + ((size_t)20<<20));    // 8 MB
  float* ymin = (float*)(ws + ((size_t)28<<20));    // 8 MB
  float* prts = (float*)(ws + ((size_t)36<<20));    // 8 MB
  float* chan = (float*)(ws + ((size_t)44<<20));    // 1 KB
  int*   fcnt = (int*)  (ws + ((size_t)45<<20));    // 3 ints
  int*   flst = (int*)  (ws + ((size_t)45<<20) + 64); // 3*4096 ints

  hipMemsetAsync(fcnt, 0, 3*sizeof(int), stream);

  // ---- layer 0: C=3 -> O=64, out channels [0,64) ----
  xx_kernel<3><<<GN/256, 256, 0, stream>>>(x, 3*NN, xxb);
  knn2_kernel<3><<<GN/16, 256, 0, stream>>>(x, 3*NN, xxb, idxb, fcnt+0, flst+0*4096);
  knn_fix_kernel<3><<<16, 256, 0, stream>>>(x, 3*NN, xxb, fcnt+0, flst+0*4096, idxb);
  pq_kernel<3,64><<<GN/64, 256, 0, stream>>>(x, 3*NN, W0, P, Q);
  stats_kernel<64><<<GN/4, 256, 0, stream>>>(P, Q, idxb, ymax, ymin, prts);
  reduce_kernel<64><<<64, 256, 0, stream>>>(prts, GN/4, g0, b0, chan);
  final_kernel<64><<<GN/64, 256, 0, stream>>>(ymax, ymin, chan, out, 0);

  // ---- layer 1: C=64 -> O=64, input = out[:,0:64,:], out channels [64,128) ----
  const float* x1 = out;
  xx_kernel<64><<<GN/256, 256, 0, stream>>>(x1, OUTC*NN, xxb);
  knn2_kernel<64><<<GN/16, 256, 0, stream>>>(x1, OUTC*NN, xxb, idxb, fcnt+1, flst+1*4096);
  knn_fix_kernel<64><<<16, 256, 0, stream>>>(x1, OUTC*NN, xxb, fcnt+1, flst+1*4096, idxb);
  pq_kernel<64,64><<<GN/64, 256, 0, stream>>>(x1, OUTC*NN, W1, P, Q);
  stats_kernel<64><<<GN/4, 256, 0, stream>>>(P, Q, idxb, ymax, ymin, prts);
  reduce_kernel<64><<<64, 256, 0, stream>>>(prts, GN/4, g1, b1, chan);
  final_kernel<64><<<GN/64, 256, 0, stream>>>(ymax, ymin, chan, out, 64);

  // ---- layer 2: C=64 -> O=128, input = out[:,64:128,:], out channels [128,256) ----
  const float* x2 = out + (size_t)64*NN;
  xx_kernel<64><<<GN/256, 256, 0, stream>>>(x2, OUTC*NN, xxb);
  knn2_kernel<64><<<GN/16, 256, 0, stream>>>(x2, OUTC*NN, xxb, idxb, fcnt+2, flst+2*4096);
  knn_fix_kernel<64><<<16, 256, 0, stream>>>(x2, OUTC*NN, xxb, fcnt+2, flst+2*4096, idxb);
  pq_kernel<64,128><<<GN/64, 256, 0, stream>>>(x2, OUTC*NN, W2, P, Q);
  stats_kernel<128><<<GN/2, 256, 0, stream>>>(P, Q, idxb, ymax, ymin, prts);
  reduce_kernel<128><<<128, 256, 0, stream>>>(prts, GN/2, g2, b2, chan);
  final_kernel<128><<<GN/64, 256, 0, stream>>>(ymax, ymin, chan, out, 128);
}